// Round 10
// baseline (742.053 us; speedup 1.0000x reference)
//
#include <hip/hip_runtime.h>
#include <hip/hip_bf16.h>

// Qwen2 decoder-layer fragment (Q path only — K/V are dead downstream):
//   h = rmsnorm(x, ln_w); q = h@Wq^T + bq; q = rope(q, pos); out = q@Wo^T + x
// out fp32 [8192, 3584].

#define HIDDEN   3584
#define NQ       3584
#define NTOK     8192
#define NPAIR    64
#define EPSV     1e-6f

typedef __hip_bfloat16 bf16;
typedef __bf16 bf16x8 __attribute__((ext_vector_type(8)));
typedef float  f32x4  __attribute__((ext_vector_type(4)));

static __device__ __forceinline__ unsigned short f2bu(float f) {
  bf16 h = __float2bfloat16(f);
  return __builtin_bit_cast(unsigned short, h);
}
static __device__ __forceinline__ void stv(float* p, float v) { *p = v; }
static __device__ __forceinline__ void stv(bf16* p, float v) { *p = __float2bfloat16(v); }

// ---------------- fp32 -> bf16 weight conversion ----------------
__global__ __launch_bounds__(256)
void cvt_f32_bf16(const float* __restrict__ s, bf16* __restrict__ d, int n4) {
  int i = blockIdx.x * 256 + threadIdx.x;
  if (i >= n4) return;
  float4 f = ((const float4*)s)[i];
  ushort4 o;
  o.x = f2bu(f.x); o.y = f2bu(f.y); o.z = f2bu(f.z); o.w = f2bu(f.w);
  ((ushort4*)d)[i] = o;
}

// ---------------- RMSNorm: x fp32 [row, 3584] -> h bf16 ----------------
__global__ __launch_bounds__(256)
void rmsnorm_k(const float* __restrict__ x, const float* __restrict__ w,
               bf16* __restrict__ h) {
  const int row = blockIdx.x;
  const int t = threadIdx.x;
  const float4* xr = (const float4*)(x + (size_t)row * HIDDEN);
  const float4* wr = (const float4*)w;

  float4 v0 = xr[t], v1 = xr[t + 256], v2 = xr[t + 512];
  float4 v3 = make_float4(0.f, 0.f, 0.f, 0.f);
  if (t < 128) v3 = xr[t + 768];

  float ss = v0.x*v0.x + v0.y*v0.y + v0.z*v0.z + v0.w*v0.w
           + v1.x*v1.x + v1.y*v1.y + v1.z*v1.z + v1.w*v1.w
           + v2.x*v2.x + v2.y*v2.y + v2.z*v2.z + v2.w*v2.w
           + v3.x*v3.x + v3.y*v3.y + v3.z*v3.z + v3.w*v3.w;

#pragma unroll
  for (int off = 32; off > 0; off >>= 1) ss += __shfl_down(ss, off);
  __shared__ float red[4];
  if ((t & 63) == 0) red[t >> 6] = ss;
  __syncthreads();
  float tot = red[0] + red[1] + red[2] + red[3];
  float scale = rsqrtf(tot * (1.0f / HIDDEN) + EPSV);

  ushort4* hr = (ushort4*)(h + (size_t)row * HIDDEN);
  float4 w0 = wr[t], w1 = wr[t + 256], w2 = wr[t + 512];
  ushort4 o;
  o.x = f2bu(v0.x*scale*w0.x); o.y = f2bu(v0.y*scale*w0.y);
  o.z = f2bu(v0.z*scale*w0.z); o.w = f2bu(v0.w*scale*w0.w);
  hr[t] = o;
  o.x = f2bu(v1.x*scale*w1.x); o.y = f2bu(v1.y*scale*w1.y);
  o.z = f2bu(v1.z*scale*w1.z); o.w = f2bu(v1.w*scale*w1.w);
  hr[t + 256] = o;
  o.x = f2bu(v2.x*scale*w2.x); o.y = f2bu(v2.y*scale*w2.y);
  o.z = f2bu(v2.z*scale*w2.z); o.w = f2bu(v2.w*scale*w2.w);
  hr[t + 512] = o;
  if (t < 128) {
    float4 w3 = wr[t + 768];
    o.x = f2bu(v3.x*scale*w3.x); o.y = f2bu(v3.y*scale*w3.y);
    o.z = f2bu(v3.z*scale*w3.z); o.w = f2bu(v3.w*scale*w3.w);
    hr[t + 768] = o;
  }
}

// ---------------- per-token rope table ----------------
__global__ __launch_bounds__(256)
void rope_tab_k(const int* __restrict__ pos, float2* __restrict__ tab) {
  int idx = blockIdx.x * 256 + threadIdx.x;   // NTOK*64
  int t = idx >> 6;
  int i = idx & 63;
  float inv = exp2f(-(float)i * (19.931568569324174f / 64.0f));
  float ang = (float)pos[t] * inv;
  float s, c;
  sincosf(ang, &s, &c);
  tab[idx] = make_float2(c, s);
}

// ---------------- in-place neox rope on q bf16 [NTOK, 28, 128] ----------------
__global__ __launch_bounds__(256)
void rope_apply_k(bf16* __restrict__ q, const float2* __restrict__ tab) {
  const int t = blockIdx.x;
  bf16* qt = q + (size_t)t * NQ;
  const float2* tb = tab + (size_t)t * NPAIR;
  for (int j = threadIdx.x; j < 28 * NPAIR; j += 256) {
    int head = j >> 6;
    int i = j & 63;
    float2 cs = tb[i];
    int base = head * 128 + i;
    float x1 = __bfloat162float(qt[base]);
    float x2 = __bfloat162float(qt[base + 64]);
    qt[base]      = __float2bfloat16(x1 * cs.x - x2 * cs.y);
    qt[base + 64] = __float2bfloat16(x2 * cs.x + x1 * cs.y);
  }
}

// ===== 256x256 8-phase bf16 GEMM (C = A * B^T), B direct-to-register ========
// 8 waves (2M x 4N), BK=64 K-tiles. A: double-buffered LDS (64 KiB) via
// gload_lds + slot^(row&7) swizzle (conflict-free, R5-verified). B: NO LDS —
// per-wave fragments loaded straight from global (L2/L3-resident weights)
// via inline-asm global_load_dwordx4, ping-pong one tile ahead (bP/bN,
// statically selected by unrolled tile parity).
// Phase mix (uniform): 4 ds_read_b128 + {ph0: stage AH1(t+1)[2 gload_lds],
// ph1: load B(t+1)[8 asm], ph2: stage AH0(t+2)[2], ph3: -}.
// RAW/WAR audit: AH1(t+1)->buf u^1 (disjoint from tile-t reads); AH0(t+2)->
// buf u at ph2 (AH0 region dead since ph1, 1-barrier sep; ph1 placement
// would race its own reads); B loads touch only registers.
// vmcnt ledger (in-order): per tile issues [AH1 2 @ph0, B 8 @ph1, AH0 2 @ph2].
// end-ph3: VMW(2) leaves exactly AH0(t+2); drains AH1(t+1)+B(t+1) (>=3-phase
// cover). sched_barrier(0) after VMW: rule-18 fence (asm-loaded B consumers
// must not hoist above the wait). Last iter: VMW(0). Prologue: B(0) 8,
// AH0(0) 2, AH1(0) 2, AH0(1) 2 -> VMW(2) leaves AH0(1).
#define BMT 256
#define BNT 256
#define BKT 64

#define BARRIER() __builtin_amdgcn_s_barrier()
#define VMW(n)    asm volatile("s_waitcnt vmcnt(" #n ")" ::: "memory")

template <int MODE, typename OutT>   // MODE 0: +bias[col] -> OutT; MODE 1: +resid[row,col]
__global__ __launch_bounds__(512, 2)
void gemm256(const bf16* __restrict__ A, const bf16* __restrict__ B,
             const float* __restrict__ aux, OutT* __restrict__ C,
             int M, int N, int K) {
  __shared__ __align__(16) bf16 sA[2][BMT][BKT];   // 64 KiB total

  const int tid  = threadIdx.x;
  const int wave = tid >> 6;     // 0..7
  const int lane = tid & 63;
  const int wm   = wave >> 2;    // 0..1
  const int wn   = wave & 3;     // 0..3
  const int fr   = lane & 15;
  const int ks   = lane >> 4;
  const int sx   = fr & 7;       // read-side slot XOR = row & 7

  // bijective XCD swizzle, bn-fast within an XCD (A panel hot in XCD L2)
  const int nwg = gridDim.x;           // 448, % 8 == 0
  const int cpx = nwg >> 3;
  const int swz = (blockIdx.x & 7) * cpx + (blockIdx.x >> 3);
  const int gn  = N / BNT;
  const int bm  = (swz / gn) * BMT;
  const int bn  = (swz % gn) * BNT;

  const bf16* Ab = A + (size_t)bm * K;
  const bf16* Bb = B + (size_t)bn * K;

  const int NT = K / BKT;   // 56 (even)

  // A staging: 64-row chunk (8KB): wave w rows [rbase+w*8,+8);
  // lane: row = l>>3, slot = l&7; source pre-swizzled slot = (l&7)^(row&7)
  const int srw = lane >> 3;    // 0..7  (== row&7)
  const int ssl = lane & 7;

  auto stage64 = [&](int kt, int buf, int rbase) {
    if (kt >= NT) return;
    const int r  = rbase + wave * 8 + srw;            // tile-local row
    const int sg = ssl ^ srw;                         // pre-swizzled source slot
    const bf16* src = Ab + (size_t)r * K + (size_t)kt * BKT + sg * 8;
    __builtin_amdgcn_global_load_lds(
        (const __attribute__((address_space(1))) void*)src,
        (__attribute__((address_space(3))) void*)(&sA[buf][rbase][0] + (size_t)(wave * 8) * BKT),
        16, 0, 0);
  };
  // A halves: H0 = rows {0-63, 128-191}; H1 = rows {64-127, 192-255}
  auto stageAH0 = [&](int kt, int buf) { stage64(kt, buf, 0);  stage64(kt, buf, 128); };
  auto stageAH1 = [&](int kt, int buf) { stage64(kt, buf, 64); stage64(kt, buf, 192); };

  f32x4 acc[8][4];
#pragma unroll
  for (int i = 0; i < 8; ++i)
#pragma unroll
    for (int j = 0; j < 4; ++j)
      acc[i][j] = (f32x4){0.f, 0.f, 0.f, 0.f};

  bf16x8 bP[4][2], bN[4][2];   // B ping/pong (static selection by tile parity)
  bf16x8 afr[2][2];            // A frags for the current phase

  // B fragment global load: frag (jf, kk): row = wn*64+jf*16+fr,
  // k = kt*64 + kk*32 + ks*8 .. +8  (16B per lane, 64B per row-quad)
  auto loadBg = [&](int kt, bf16x8 (&dst)[4][2]) {
    if (kt >= NT) return;
#pragma unroll
    for (int jf = 0; jf < 4; ++jf)
#pragma unroll
      for (int kk = 0; kk < 2; ++kk) {
        const bf16* src = Bb + (size_t)(wn * 64 + jf * 16 + fr) * K
                             + (size_t)kt * BKT + kk * 32 + ks * 8;
        asm volatile("global_load_dwordx4 %0, %1, off"
                     : "=v"(dst[jf][kk]) : "v"(src) : "memory");
      }
  };

  auto loadA = [&](int buf, int qq) {
#pragma unroll
    for (int i = 0; i < 2; ++i)
#pragma unroll
      for (int kk = 0; kk < 2; ++kk) {
        const int R  = wm * 128 + qq * 32 + i * 16 + fr;
        const int sp = (kk * 4 + ks) ^ sx;
        afr[i][kk] = *(const bf16x8*)&sA[buf][R][sp * 8];
      }
  };
  auto domfma = [&](int q, bf16x8 (&bc)[4][2]) {
#pragma unroll
    for (int i = 0; i < 2; ++i)
#pragma unroll
      for (int j = 0; j < 4; ++j)
#pragma unroll
        for (int kk = 0; kk < 2; ++kk)
          acc[q * 2 + i][j] = __builtin_amdgcn_mfma_f32_16x16x32_bf16(
              afr[i][kk], bc[j][kk], acc[q * 2 + i][j], 0, 0, 0);
  };

  // prologue: B(0)->bP (8), AH0(0) (2), AH1(0) (2), AH0(1) (2); VMW(2)
  // leaves AH0(1); everything tile-0 needs is landed.
  loadBg(0, bP);
  stageAH0(0, 0); stageAH1(0, 0); stageAH0(1, 1);
  VMW(2);
  __builtin_amdgcn_sched_barrier(0);
  BARRIER();

  const int nit = NT / 2;   // 28

  for (int it = 0; it < nit; ++it) {
    const bool last = (it == nit - 1);
#pragma unroll
    for (int u = 0; u < 2; ++u) {          // tile kt = 2*it+u, buf u
      const int kt = 2 * it + u;
#pragma unroll
      for (int q = 0; q < 4; ++q) {        // phase within tile
        // ---- ds_read this phase's A fragments ----
        loadA(u, q);
        // ---- prefetch issue (see ledger) ----
        if (q == 0)      stageAH1(kt + 1, u ^ 1);           // 2 gload_lds
        else if (q == 1) { if (u == 0) loadBg(kt + 1, bN);  // 8 asm loads
                           else        loadBg(kt + 1, bP); }
        else if (q == 2) stageAH0(kt + 2, u);               // 2 gload_lds
        BARRIER();
        __builtin_amdgcn_s_setprio(1);
        if (u == 0) domfma(q, bP);
        else        domfma(q, bN);
        __builtin_amdgcn_s_setprio(0);
        if (q == 3) {
          if (!last) { VMW(2); } else { VMW(0); }
          __builtin_amdgcn_sched_barrier(0);
        }
        BARRIER();
      }
    }
  }

  // epilogue: C/D layout col = lane&15, row = 4*(lane>>4) + reg
#pragma unroll
  for (int f = 0; f < 8; ++f) {
    const int rb = bm + wm * 128 + f * 16 + ks * 4;
#pragma unroll
    for (int j = 0; j < 4; ++j) {
      const int col = bn + wn * 64 + j * 16 + fr;
#pragma unroll
      for (int r = 0; r < 4; ++r) {
        const int row = rb + r;
        float v = acc[f][j][r];
        if (MODE == 0) v += aux[col];
        else           v += aux[(size_t)row * N + col];
        stv(&C[(size_t)row * N + col], v);
      }
    }
  }
}

// ---------------- launch ----------------
extern "C" void kernel_launch(void* const* d_in, const int* in_sizes, int n_in,
                              void* d_out, int out_size, void* d_ws, size_t ws_size,
                              hipStream_t stream) {
  (void)in_sizes; (void)n_in; (void)out_size; (void)ws_size;
  const float* x    = (const float*)d_in[0];
  const int*   pos  = (const int*)d_in[1];
  const float* ln_w = (const float*)d_in[2];
  const float* Wq   = (const float*)d_in[3];
  const float* bq   = (const float*)d_in[4];
  const float* Wo   = (const float*)d_in[9];
  float* out = (float*)d_out;

  char* ws = (char*)d_ws;
  size_t off = 0;
  bf16* h    = (bf16*)(ws + off); off += (size_t)NTOK * HIDDEN * sizeof(bf16);
  bf16* q    = (bf16*)(ws + off); off += (size_t)NTOK * NQ * sizeof(bf16);
  bf16* Wqb  = (bf16*)(ws + off); off += (size_t)NQ * HIDDEN * sizeof(bf16);
  bf16* Wob  = (bf16*)(ws + off); off += (size_t)HIDDEN * NQ * sizeof(bf16);
  float2* tab = (float2*)(ws + off); off += (size_t)NTOK * NPAIR * sizeof(float2);

  const int n4 = NQ * HIDDEN / 4;
  cvt_f32_bf16<<<(n4 + 255) / 256, 256, 0, stream>>>(Wq, Wqb, n4);
  cvt_f32_bf16<<<(n4 + 255) / 256, 256, 0, stream>>>(Wo, Wob, n4);
  rmsnorm_k<<<NTOK, 256, 0, stream>>>(x, ln_w, h);
  rope_tab_k<<<(NTOK * NPAIR) / 256, 256, 0, stream>>>(pos, tab);

  const int nblk = (NTOK / BMT) * (NQ / BNT);   // 32 * 14 = 448 (%8 == 0)
  gemm256<0, bf16><<<nblk, 512, 0, stream>>>(h, Wqb, bq, q, NTOK, NQ, HIDDEN);
  rope_apply_k<<<NTOK, 256, 0, stream>>>(q, tab);
  gemm256<1, float><<<nblk, 512, 0, stream>>>(q, Wob, x, out, NTOK, HIDDEN, NQ);
}

// Round 12
// 595.655 us; speedup vs baseline: 1.2458x; 1.2458x over previous
//
#include <hip/hip_runtime.h>
#include <hip/hip_bf16.h>

// Qwen2 decoder-layer fragment (Q path only — K/V are dead downstream):
//   h = rmsnorm(x, ln_w); q = h@Wq^T + bq; q = rope(q, pos); out = q@Wo^T + x
// out fp32 [8192, 3584].

#define HIDDEN   3584
#define NQ       3584
#define NTOK     8192
#define NPAIR    64
#define EPSV     1e-6f

typedef __hip_bfloat16 bf16;
typedef __bf16 bf16x8 __attribute__((ext_vector_type(8)));
typedef float  f32x4  __attribute__((ext_vector_type(4)));

static __device__ __forceinline__ unsigned short f2bu(float f) {
  bf16 h = __float2bfloat16(f);
  return __builtin_bit_cast(unsigned short, h);
}
static __device__ __forceinline__ void stv(float* p, float v) { *p = v; }
static __device__ __forceinline__ void stv(bf16* p, float v) { *p = __float2bfloat16(v); }

// ---------------- fp32 -> bf16 weight conversion ----------------
__global__ __launch_bounds__(256)
void cvt_f32_bf16(const float* __restrict__ s, bf16* __restrict__ d, int n4) {
  int i = blockIdx.x * 256 + threadIdx.x;
  if (i >= n4) return;
  float4 f = ((const float4*)s)[i];
  ushort4 o;
  o.x = f2bu(f.x); o.y = f2bu(f.y); o.z = f2bu(f.z); o.w = f2bu(f.w);
  ((ushort4*)d)[i] = o;
}

// ---------------- RMSNorm: x fp32 [row, 3584] -> h bf16 ----------------
__global__ __launch_bounds__(256)
void rmsnorm_k(const float* __restrict__ x, const float* __restrict__ w,
               bf16* __restrict__ h) {
  const int row = blockIdx.x;
  const int t = threadIdx.x;
  const float4* xr = (const float4*)(x + (size_t)row * HIDDEN);
  const float4* wr = (const float4*)w;

  float4 v0 = xr[t], v1 = xr[t + 256], v2 = xr[t + 512];
  float4 v3 = make_float4(0.f, 0.f, 0.f, 0.f);
  if (t < 128) v3 = xr[t + 768];

  float ss = v0.x*v0.x + v0.y*v0.y + v0.z*v0.z + v0.w*v0.w
           + v1.x*v1.x + v1.y*v1.y + v1.z*v1.z + v1.w*v1.w
           + v2.x*v2.x + v2.y*v2.y + v2.z*v2.z + v2.w*v2.w
           + v3.x*v3.x + v3.y*v3.y + v3.z*v3.z + v3.w*v3.w;

#pragma unroll
  for (int off = 32; off > 0; off >>= 1) ss += __shfl_down(ss, off);
  __shared__ float red[4];
  if ((t & 63) == 0) red[t >> 6] = ss;
  __syncthreads();
  float tot = red[0] + red[1] + red[2] + red[3];
  float scale = rsqrtf(tot * (1.0f / HIDDEN) + EPSV);

  ushort4* hr = (ushort4*)(h + (size_t)row * HIDDEN);
  float4 w0 = wr[t], w1 = wr[t + 256], w2 = wr[t + 512];
  ushort4 o;
  o.x = f2bu(v0.x*scale*w0.x); o.y = f2bu(v0.y*scale*w0.y);
  o.z = f2bu(v0.z*scale*w0.z); o.w = f2bu(v0.w*scale*w0.w);
  hr[t] = o;
  o.x = f2bu(v1.x*scale*w1.x); o.y = f2bu(v1.y*scale*w1.y);
  o.z = f2bu(v1.z*scale*w1.z); o.w = f2bu(v1.w*scale*w1.w);
  hr[t + 256] = o;
  o.x = f2bu(v2.x*scale*w2.x); o.y = f2bu(v2.y*scale*w2.y);
  o.z = f2bu(v2.z*scale*w2.z); o.w = f2bu(v2.w*scale*w2.w);
  hr[t + 512] = o;
  if (t < 128) {
    float4 w3 = wr[t + 768];
    o.x = f2bu(v3.x*scale*w3.x); o.y = f2bu(v3.y*scale*w3.y);
    o.z = f2bu(v3.z*scale*w3.z); o.w = f2bu(v3.w*scale*w3.w);
    hr[t + 768] = o;
  }
}

// ---------------- per-token rope table ----------------
__global__ __launch_bounds__(256)
void rope_tab_k(const int* __restrict__ pos, float2* __restrict__ tab) {
  int idx = blockIdx.x * 256 + threadIdx.x;   // NTOK*64
  int t = idx >> 6;
  int i = idx & 63;
  float inv = exp2f(-(float)i * (19.931568569324174f / 64.0f));
  float ang = (float)pos[t] * inv;
  float s, c;
  sincosf(ang, &s, &c);
  tab[idx] = make_float2(c, s);
}

// ---------------- in-place neox rope on q bf16 [NTOK, 28, 128] ----------------
__global__ __launch_bounds__(256)
void rope_apply_k(bf16* __restrict__ q, const float2* __restrict__ tab) {
  const int t = blockIdx.x;
  bf16* qt = q + (size_t)t * NQ;
  const float2* tb = tab + (size_t)t * NPAIR;
  for (int j = threadIdx.x; j < 28 * NPAIR; j += 256) {
    int head = j >> 6;
    int i = j & 63;
    float2 cs = tb[i];
    int base = head * 128 + i;
    float x1 = __bfloat162float(qt[base]);
    float x2 = __bfloat162float(qt[base + 64]);
    qt[base]      = __float2bfloat16(x1 * cs.x - x2 * cs.y);
    qt[base + 64] = __float2bfloat16(x2 * cs.x + x1 * cs.y);
  }
}

// ====== 128x128 2-phase bf16 GEMM (C = A * B^T), 2 blocks/CU co-resident ====
// 8 waves, BK=64, double-buffered LDS = 64 KiB -> 2 blocks/CU.
// R12 FIX (R11 RAW race): row split is PHASE-major, not wave-major —
//   phase half reads rows half*64 + wm*32 + i*16 + fr  (all waves stay inside
//   the half-guarded staging region; R11's wm*64+... let wm=1 waves read the
//   Ahi region in phase 0, before its VMW drain).
// Per K-tile (buf u, stages -> buf u^1):
//  ph0: read B(t) [4 ds] + A rows 0-63 [4 ds]; stage Blo,Bhi,Alo(t+1) [3];
//       bar; 8 MFMA; VMW(3) (last tile VMW(0)); bar
//  ph1: read A rows 64-127 [4 ds]; stage Ahi(t+1) [1]; bar; 8 MFMA; VMW(1); bar
// Ledger (1 instr/stage): end-ph1(t-1) leaves [Ahi(t)]; ph0(t) +3 -> 4;
// VMW(3) drains Ahi(t) (guards ph1 reads). ph1(t) +1 -> 4; VMW(1) drains
// B(t+1)+Alo(t+1) (guards next ph0), leaves Ahi(t+1). Last tile: VMW(0).
// RAW: B/Alo(t) drained end-ph1(t-1)+bar; Ahi(t) drained end-ph0(t)+bar.
// WAR: stages write buf u^1; its last reader finished >=1 barrier earlier.
// Reads can't hoist above the guarding VMW (asm memory clobber); barriers
// themselves are soft (no clobber) so MFMA/sched may overlap freely.
// Swizzle slot^(row&7) (row&7==fr&7 here), conflict-free (R5-verified).
#define BMT 128
#define BNT 128
#define BKT 64

#define BARRIER() __builtin_amdgcn_s_barrier()
#define VMW(n)    asm volatile("s_waitcnt vmcnt(" #n ")" ::: "memory")

template <int MODE, typename OutT>   // MODE 0: +bias[col] -> OutT; MODE 1: +resid[row,col]
__global__ __launch_bounds__(512, 4)
void gemm128(const bf16* __restrict__ A, const bf16* __restrict__ B,
             const float* __restrict__ aux, OutT* __restrict__ C,
             int M, int N, int K) {
  __shared__ __align__(16) bf16 sA[2][BMT][BKT];   // 32 KiB
  __shared__ __align__(16) bf16 sB[2][BNT][BKT];   // 32 KiB

  const int tid  = threadIdx.x;
  const int wave = tid >> 6;     // 0..7
  const int lane = tid & 63;
  const int wm   = wave >> 2;    // 0..1  (32-row slice within each 64-row half)
  const int wn   = wave & 3;     // 0..3  (32-col quarter)
  const int fr   = lane & 15;
  const int ks   = lane >> 4;
  const int sx   = fr & 7;       // read-side slot XOR = row & 7

  // bijective XCD swizzle, bn-fast within an XCD
  const int nwg = gridDim.x;           // 1792, % 8 == 0
  const int cpx = nwg >> 3;
  const int swz = (blockIdx.x & 7) * cpx + (blockIdx.x >> 3);
  const int gn  = N / BNT;             // 28
  const int bm  = (swz / gn) * BMT;
  const int bn  = (swz % gn) * BNT;

  const bf16* Ab = A + (size_t)bm * K;
  const bf16* Bb = B + (size_t)bn * K;

  const int NT = K / BKT;   // 56

  // staging: one instr covers 64 rows (8 waves x 8 rows); lane: row=l>>3,
  // slot=l&7; source pre-swizzled slot = (l&7)^(row&7)
  const int srw = lane >> 3;    // 0..7 (== row&7)
  const int ssl = lane & 7;

  auto stage64 = [&](const bf16* gpanel, int kt, bf16* ldst, int rbase) {
    if (kt >= NT) return;
    const int r  = rbase + wave * 8 + srw;            // tile-local row
    const int sg = ssl ^ srw;                         // pre-swizzled source slot
    const bf16* src = gpanel + (size_t)r * K + (size_t)kt * BKT + sg * 8;
    __builtin_amdgcn_global_load_lds(
        (const __attribute__((address_space(1))) void*)src,
        (__attribute__((address_space(3))) void*)(ldst + (size_t)(rbase + wave * 8) * BKT),
        16, 0, 0);
  };

  f32x4 acc[4][2];
#pragma unroll
  for (int i = 0; i < 4; ++i)
#pragma unroll
    for (int j = 0; j < 2; ++j)
      acc[i][j] = (f32x4){0.f, 0.f, 0.f, 0.f};

  bf16x8 bfr[2][2];   // B frags [n][kk], loaded at ph0, live both phases
  bf16x8 afr[2][2];   // A frags [m][kk] for the current phase

  auto loadA = [&](int buf, int half) {   // phase-major: rows half*64 + wm*32 + ...
#pragma unroll
    for (int i = 0; i < 2; ++i)
#pragma unroll
      for (int kk = 0; kk < 2; ++kk) {
        const int R  = half * 64 + wm * 32 + i * 16 + fr;
        const int sp = (kk * 4 + ks) ^ sx;
        afr[i][kk] = *(const bf16x8*)&sA[buf][R][sp * 8];
      }
  };
  auto loadB = [&](int buf) {
#pragma unroll
    for (int j = 0; j < 2; ++j)
#pragma unroll
      for (int kk = 0; kk < 2; ++kk) {
        const int R  = wn * 32 + j * 16 + fr;
        const int sp = (kk * 4 + ks) ^ sx;
        bfr[j][kk] = *(const bf16x8*)&sB[buf][R][sp * 8];
      }
  };
  auto domfma = [&](int half) {
#pragma unroll
    for (int i = 0; i < 2; ++i)
#pragma unroll
      for (int j = 0; j < 2; ++j)
#pragma unroll
        for (int kk = 0; kk < 2; ++kk)
          acc[half * 2 + i][j] = __builtin_amdgcn_mfma_f32_16x16x32_bf16(
              afr[i][kk], bfr[j][kk], acc[half * 2 + i][j], 0, 0, 0);
  };

  // prologue: tile0 fully staged (4 instr), drained
  stage64(Bb, 0, &sB[0][0][0], 0);  stage64(Bb, 0, &sB[0][0][0], 64);
  stage64(Ab, 0, &sA[0][0][0], 0);  stage64(Ab, 0, &sA[0][0][0], 64);
  VMW(0);
  BARRIER();

  for (int it = 0; it < NT / 2; ++it) {
#pragma unroll
    for (int u = 0; u < 2; ++u) {
      const int kt = 2 * it + u;
      const bool lastt = (kt == NT - 1);
      // ---- phase 0: B + A rows 0-63 ----
      loadA(u, 0);
      loadB(u);
      stage64(Bb, kt + 1, &sB[u ^ 1][0][0], 0);
      stage64(Bb, kt + 1, &sB[u ^ 1][0][0], 64);
      stage64(Ab, kt + 1, &sA[u ^ 1][0][0], 0);
      BARRIER();
      __builtin_amdgcn_s_setprio(1);
      domfma(0);
      __builtin_amdgcn_s_setprio(0);
      if (lastt) { VMW(0); } else { VMW(3); }
      BARRIER();
      // ---- phase 1: A rows 64-127 ----
      loadA(u, 1);
      stage64(Ab, kt + 1, &sA[u ^ 1][0][0], 64);
      BARRIER();
      __builtin_amdgcn_s_setprio(1);
      domfma(1);
      __builtin_amdgcn_s_setprio(0);
      if (lastt) { VMW(0); } else { VMW(1); }
      BARRIER();
    }
  }

  // epilogue: C/D layout col = lane&15, row = 4*(lane>>4) + reg
#pragma unroll
  for (int half = 0; half < 2; ++half) {
#pragma unroll
    for (int i = 0; i < 2; ++i) {
      const int rb = bm + half * 64 + wm * 32 + i * 16 + ks * 4;
#pragma unroll
      for (int j = 0; j < 2; ++j) {
        const int col = bn + wn * 32 + j * 16 + fr;
#pragma unroll
        for (int r = 0; r < 4; ++r) {
          const int row = rb + r;
          float v = acc[half * 2 + i][j][r];
          if (MODE == 0) v += aux[col];
          else           v += aux[(size_t)row * N + col];
          stv(&C[(size_t)row * N + col], v);
        }
      }
    }
  }
}

// ---------------- launch ----------------
extern "C" void kernel_launch(void* const* d_in, const int* in_sizes, int n_in,
                              void* d_out, int out_size, void* d_ws, size_t ws_size,
                              hipStream_t stream) {
  (void)in_sizes; (void)n_in; (void)out_size; (void)ws_size;
  const float* x    = (const float*)d_in[0];
  const int*   pos  = (const int*)d_in[1];
  const float* ln_w = (const float*)d_in[2];
  const float* Wq   = (const float*)d_in[3];
  const float* bq   = (const float*)d_in[4];
  const float* Wo   = (const float*)d_in[9];
  float* out = (float*)d_out;

  char* ws = (char*)d_ws;
  size_t off = 0;
  bf16* h    = (bf16*)(ws + off); off += (size_t)NTOK * HIDDEN * sizeof(bf16);
  bf16* q    = (bf16*)(ws + off); off += (size_t)NTOK * NQ * sizeof(bf16);
  bf16* Wqb  = (bf16*)(ws + off); off += (size_t)NQ * HIDDEN * sizeof(bf16);
  bf16* Wob  = (bf16*)(ws + off); off += (size_t)HIDDEN * NQ * sizeof(bf16);
  float2* tab = (float2*)(ws + off); off += (size_t)NTOK * NPAIR * sizeof(float2);

  const int n4 = NQ * HIDDEN / 4;
  cvt_f32_bf16<<<(n4 + 255) / 256, 256, 0, stream>>>(Wq, Wqb, n4);
  cvt_f32_bf16<<<(n4 + 255) / 256, 256, 0, stream>>>(Wo, Wob, n4);
  rmsnorm_k<<<NTOK, 256, 0, stream>>>(x, ln_w, h);
  rope_tab_k<<<(NTOK * NPAIR) / 256, 256, 0, stream>>>(pos, tab);

  const int nblk = (NTOK / BMT) * (NQ / BNT);   // 64 * 28 = 1792 (%8 == 0)
  gemm128<0, bf16><<<nblk, 512, 0, stream>>>(h, Wqb, bq, q, NTOK, NQ, HIDDEN);
  rope_apply_k<<<NTOK, 256, 0, stream>>>(q, tab);
  gemm128<1, float><<<nblk, 512, 0, stream>>>(q, Wob, x, out, NTOK, HIDDEN, NQ);
}

// Round 13
// 533.657 us; speedup vs baseline: 1.3905x; 1.1162x over previous
//
#include <hip/hip_runtime.h>
#include <hip/hip_bf16.h>

// Qwen2 decoder-layer fragment (Q path only — K/V are dead downstream):
//   h = rmsnorm(x, ln_w); q = h@Wq^T + bq; q = rope(q, pos); out = q@Wo^T + x
// out fp32 [8192, 3584].

#define HIDDEN   3584
#define NQ       3584
#define NTOK     8192
#define NPAIR    64
#define EPSV     1e-6f

typedef __hip_bfloat16 bf16;
typedef __bf16 bf16x8 __attribute__((ext_vector_type(8)));
typedef float  f32x4  __attribute__((ext_vector_type(4)));

static __device__ __forceinline__ unsigned short f2bu(float f) {
  bf16 h = __float2bfloat16(f);
  return __builtin_bit_cast(unsigned short, h);
}
static __device__ __forceinline__ void stv(float* p, float v) { *p = v; }
static __device__ __forceinline__ void stv(bf16* p, float v) { *p = __float2bfloat16(v); }

// ---------------- fp32 -> bf16 weight conversion ----------------
__global__ __launch_bounds__(256)
void cvt_f32_bf16(const float* __restrict__ s, bf16* __restrict__ d, int n4) {
  int i = blockIdx.x * 256 + threadIdx.x;
  if (i >= n4) return;
  float4 f = ((const float4*)s)[i];
  ushort4 o;
  o.x = f2bu(f.x); o.y = f2bu(f.y); o.z = f2bu(f.z); o.w = f2bu(f.w);
  ((ushort4*)d)[i] = o;
}

// ---------------- RMSNorm: x fp32 [row, 3584] -> h bf16 ----------------
__global__ __launch_bounds__(256)
void rmsnorm_k(const float* __restrict__ x, const float* __restrict__ w,
               bf16* __restrict__ h) {
  const int row = blockIdx.x;
  const int t = threadIdx.x;
  const float4* xr = (const float4*)(x + (size_t)row * HIDDEN);
  const float4* wr = (const float4*)w;

  float4 v0 = xr[t], v1 = xr[t + 256], v2 = xr[t + 512];
  float4 v3 = make_float4(0.f, 0.f, 0.f, 0.f);
  if (t < 128) v3 = xr[t + 768];

  float ss = v0.x*v0.x + v0.y*v0.y + v0.z*v0.z + v0.w*v0.w
           + v1.x*v1.x + v1.y*v1.y + v1.z*v1.z + v1.w*v1.w
           + v2.x*v2.x + v2.y*v2.y + v2.z*v2.z + v2.w*v2.w
           + v3.x*v3.x + v3.y*v3.y + v3.z*v3.z + v3.w*v3.w;

#pragma unroll
  for (int off = 32; off > 0; off >>= 1) ss += __shfl_down(ss, off);
  __shared__ float red[4];
  if ((t & 63) == 0) red[t >> 6] = ss;
  __syncthreads();
  float tot = red[0] + red[1] + red[2] + red[3];
  float scale = rsqrtf(tot * (1.0f / HIDDEN) + EPSV);

  ushort4* hr = (ushort4*)(h + (size_t)row * HIDDEN);
  float4 w0 = wr[t], w1 = wr[t + 256], w2 = wr[t + 512];
  ushort4 o;
  o.x = f2bu(v0.x*scale*w0.x); o.y = f2bu(v0.y*scale*w0.y);
  o.z = f2bu(v0.z*scale*w0.z); o.w = f2bu(v0.w*scale*w0.w);
  hr[t] = o;
  o.x = f2bu(v1.x*scale*w1.x); o.y = f2bu(v1.y*scale*w1.y);
  o.z = f2bu(v1.z*scale*w1.z); o.w = f2bu(v1.w*scale*w1.w);
  hr[t + 256] = o;
  o.x = f2bu(v2.x*scale*w2.x); o.y = f2bu(v2.y*scale*w2.y);
  o.z = f2bu(v2.z*scale*w2.z); o.w = f2bu(v2.w*scale*w2.w);
  hr[t + 512] = o;
  if (t < 128) {
    float4 w3 = wr[t + 768];
    o.x = f2bu(v3.x*scale*w3.x); o.y = f2bu(v3.y*scale*w3.y);
    o.z = f2bu(v3.z*scale*w3.z); o.w = f2bu(v3.w*scale*w3.w);
    hr[t + 768] = o;
  }
}

// ---------------- per-token rope table ----------------
__global__ __launch_bounds__(256)
void rope_tab_k(const int* __restrict__ pos, float2* __restrict__ tab) {
  int idx = blockIdx.x * 256 + threadIdx.x;   // NTOK*64
  int t = idx >> 6;
  int i = idx & 63;
  float inv = exp2f(-(float)i * (19.931568569324174f / 64.0f));
  float ang = (float)pos[t] * inv;
  float s, c;
  sincosf(ang, &s, &c);
  tab[idx] = make_float2(c, s);
}

// ---------------- in-place neox rope on q bf16 [NTOK, 28, 128] ----------------
__global__ __launch_bounds__(256)
void rope_apply_k(bf16* __restrict__ q, const float2* __restrict__ tab) {
  const int t = blockIdx.x;
  bf16* qt = q + (size_t)t * NQ;
  const float2* tb = tab + (size_t)t * NPAIR;
  for (int j = threadIdx.x; j < 28 * NPAIR; j += 256) {
    int head = j >> 6;
    int i = j & 63;
    float2 cs = tb[i];
    int base = head * 128 + i;
    float x1 = __bfloat162float(qt[base]);
    float x2 = __bfloat162float(qt[base + 64]);
    qt[base]      = __float2bfloat16(x1 * cs.x - x2 * cs.y);
    qt[base + 64] = __float2bfloat16(x2 * cs.x + x1 * cs.y);
  }
}

// ================= 256x256 8-phase bf16 GEMM (C = A * B^T) ==================
// 8 waves (2M x 4N), BK=64 K-tiles, double-buffered LDS (128 KiB).
// R13: POST-MFMA READS, 1 barrier/phase. Phase p issues phase p+1's ds_reads
// AFTER its MFMA cluster -> a wave done with MFMA issues reads while other
// waves still hold the MFMA pipe; the LDS drain hides under MFMA instead of
// serializing before it (this was the measured ~1340-cyc/phase decomposition:
// 620 MFMA + ~380 LDS drain + sync, serial). Barriers: 8/iter (was 16).
// Phase p = {BAR; stage(p); setprio+16 MFMA+setprio; [VMW]; reads(p+1)}.
// Stagger: ph0:AH1(o,b1) ph1:Blo(e2,b0) ph2:Bhi(e2,b0) ph3:AH0(e2,b0)
//          ph4:AH1(e2,b0) ph5:Blo(o2,b1) ph6:Bhi(o2,b1) ph7:AH0(o2,b1)
//          (e=2it,o=2it+1,e2=2it+2,o2=2it+3; tile t -> buf t&1)
// vmcnt: VMW(4) at end-ph2 (drains ALL of tile o: carry{B,AH0(o)}+ph0{AH1(o)};
// leaves ph1,2 = B(e2)) and end-ph6 (drains all of tile e2; leaves B(o2)).
// Covered youngest load has 2 phases (~1400 cyc > 900 HBM). Last iter: VMW(0).
// Tile-crossing q0 reads (end-ph3/ph7) are ordered after every wave's VMW by
// the LEADING barriers of ph3/ph7, which are ASM-CLOBBER barriers (plain
// builtin barriers carry no LLVM memory clobber, so those reads could hoist
// above them; the VMW asm clobbers bound all other hoists). q1-q3 reads touch
// data drained >=1 iteration ago — safe under any bounded hoist.
// WAR per stage: region's last consumer MFMA is >=1 barrier before the stage
// issue (checked per phase). Swizzle slot^(row&7): conflict-free (R5: 0).
#define BMT 256
#define BNT 256
#define BKT 64

#define BARRIER()  __builtin_amdgcn_s_barrier()
#define BARRIERC() asm volatile("s_barrier" ::: "memory")
#define VMW(n)     asm volatile("s_waitcnt vmcnt(" #n ")" ::: "memory")

template <int MODE, typename OutT>   // MODE 0: +bias[col] -> OutT; MODE 1: +resid[row,col]
__global__ __launch_bounds__(512, 2)
void gemm256(const bf16* __restrict__ A, const bf16* __restrict__ B,
             const float* __restrict__ aux, OutT* __restrict__ C,
             int M, int N, int K) {
  __shared__ __align__(16) bf16 sA[2][BMT][BKT];   // 64 KiB
  __shared__ __align__(16) bf16 sB[2][BNT][BKT];   // 64 KiB

  const int tid  = threadIdx.x;
  const int wave = tid >> 6;     // 0..7
  const int lane = tid & 63;
  const int wm   = wave >> 2;    // 0..1
  const int wn   = wave & 3;     // 0..3
  const int fr   = lane & 15;
  const int ks   = lane >> 4;
  const int sx   = fr & 7;       // read-side slot XOR = row & 7

  // bijective XCD swizzle, bn-fast within an XCD (A panel hot in XCD L2)
  const int nwg = gridDim.x;           // 448, % 8 == 0
  const int cpx = nwg >> 3;
  const int swz = (blockIdx.x & 7) * cpx + (blockIdx.x >> 3);
  const int gn  = N / BNT;
  const int bm  = (swz / gn) * BMT;
  const int bn  = (swz % gn) * BNT;

  const bf16* Ab = A + (size_t)bm * K;
  const bf16* Bb = B + (size_t)bn * K;

  const int NT = K / BKT;   // 56 (even)

  // staging: one 64-row chunk (8KB): wave w rows [rbase+w*8,+8);
  // lane: row = l>>3, slot = l&7; source pre-swizzled slot = (l&7)^(row&7)
  const int srw = lane >> 3;    // 0..7  (== row&7)
  const int ssl = lane & 7;

  auto stage64 = [&](const bf16* gpanel, int kt, bf16* ldst, int rbase) {
    const int r  = rbase + wave * 8 + srw;            // tile-local row
    const int sg = ssl ^ srw;                         // pre-swizzled source slot
    const bf16* src = gpanel + (size_t)r * K + (size_t)kt * BKT + sg * 8;
    __builtin_amdgcn_global_load_lds(
        (const __attribute__((address_space(1))) void*)src,
        (__attribute__((address_space(3))) void*)(ldst + (size_t)(wave * 8) * BKT),
        16, 0, 0);
  };
  // kinds: 0=A_H0{0,128}, 1=A_H1{64,192}, 2=B_lo{0,64}, 3=B_hi{128,192}
  auto stage16k = [&](int kind, int buf, int kt) {
    if (kt >= NT) return;
    if (kind == 0)      { stage64(Ab, kt, &sA[buf][0][0],   0);   stage64(Ab, kt, &sA[buf][128][0], 128); }
    else if (kind == 1) { stage64(Ab, kt, &sA[buf][64][0],  64);  stage64(Ab, kt, &sA[buf][192][0], 192); }
    else if (kind == 2) { stage64(Bb, kt, &sB[buf][0][0],   0);   stage64(Bb, kt, &sB[buf][64][0],  64); }
    else                { stage64(Bb, kt, &sB[buf][128][0], 128); stage64(Bb, kt, &sB[buf][192][0], 192); }
  };

  f32x4 acc[8][4];
#pragma unroll
  for (int i = 0; i < 8; ++i)
#pragma unroll
    for (int j = 0; j < 4; ++j)
      acc[i][j] = (f32x4){0.f, 0.f, 0.f, 0.f};

  bf16x8 bfr[4][2];       // B frags for the current tile (single set; reloaded
                          // at end-ph3/ph7 AFTER last MFMA use — anti-dep)
  bf16x8 afr[2][2];       // A frags for the current phase (single set)

  auto loadA = [&](int buf, int qq) {
#pragma unroll
    for (int i = 0; i < 2; ++i)
#pragma unroll
      for (int kk = 0; kk < 2; ++kk) {
        const int R  = wm * 128 + qq * 32 + i * 16 + fr;
        const int sp = (kk * 4 + ks) ^ sx;
        afr[i][kk] = *(const bf16x8*)&sA[buf][R][sp * 8];
      }
  };
  auto loadB = [&](int buf) {
#pragma unroll
    for (int j = 0; j < 4; ++j)
#pragma unroll
      for (int kk = 0; kk < 2; ++kk) {
        const int R  = wn * 64 + j * 16 + fr;
        const int sp = (kk * 4 + ks) ^ sx;
        bfr[j][kk] = *(const bf16x8*)&sB[buf][R][sp * 8];
      }
  };
  auto domfma = [&](int q) {
#pragma unroll
    for (int i = 0; i < 2; ++i)
#pragma unroll
      for (int j = 0; j < 4; ++j)
#pragma unroll
        for (int kk = 0; kk < 2; ++kk)
          acc[q * 2 + i][j] = __builtin_amdgcn_mfma_f32_16x16x32_bf16(
              afr[i][kk], bfr[j][kk], acc[q * 2 + i][j], 0, 0, 0);
  };

  // prologue: tile0 complete (8 loads), tile1 B + A_H0 (6 loads);
  // VMW(6) drains tile0 (leaves the 6 tile-1 loads = steady carry-in);
  // clobber barrier orders every wave's drain before the first reads.
  stage16k(2, 0, 0); stage16k(3, 0, 0); stage16k(0, 0, 0); stage16k(1, 0, 0);
  stage16k(2, 1, 1); stage16k(3, 1, 1); stage16k(0, 1, 1);
  VMW(6);
  BARRIERC();
  loadB(0);
  loadA(0, 0);

  const int nit = NT / 2;   // 28

  for (int it = 0; it < nit; ++it) {
    const bool last = (it == nit - 1);
#pragma unroll
    for (int u = 0; u < 2; ++u) {          // tile kt = 2*it+u, buf u
#pragma unroll
      for (int q = 0; q < 4; ++q) {        // phase within tile
        const int ph = u * 4 + q;
        // ---- leading barrier (clobbered at the tile-crossing phases) ----
        if (ph == 3 || ph == 7) BARRIERC();
        else                    BARRIER();
        // ---- staggered 16KB stage (region's readers done >=1 bar ago) ----
        if (ph == 0)      stage16k(1, 1, 2 * it + 1);   // A_H1 of tile 2it+1
        else if (ph == 1) stage16k(2, 0, 2 * it + 2);   // B_lo  tile 2it+2
        else if (ph == 2) stage16k(3, 0, 2 * it + 2);   // B_hi
        else if (ph == 3) stage16k(0, 0, 2 * it + 2);   // A_H0
        else if (ph == 4) stage16k(1, 0, 2 * it + 2);   // A_H1
        else if (ph == 5) stage16k(2, 1, 2 * it + 3);   // B_lo  tile 2it+3
        else if (ph == 6) stage16k(3, 1, 2 * it + 3);   // B_hi
        else              stage16k(0, 1, 2 * it + 3);   // A_H0
        // ---- MFMA on operands read at the end of the previous phase ----
        __builtin_amdgcn_s_setprio(1);
        domfma(q);
        __builtin_amdgcn_s_setprio(0);
        // ---- counted vmcnt (one phase BEFORE the crossing reads) ----
        if (ph == 2 || ph == 6) {
          if (last) { VMW(0); } else { VMW(4); }
        }
        // ---- issue next phase's reads (post-MFMA: drain hides under
        //      other waves' MFMA) ----
        if (q < 3) {
          loadA(u, q + 1);
        } else if (!(last && u == 1)) {
          loadB(u ^ 1);        // next tile's B (staged & drained; bar-ordered)
          loadA(u ^ 1, 0);     // next tile's A q0
        }
      }
    }
  }

  // epilogue: C/D layout col = lane&15, row = 4*(lane>>4) + reg
#pragma unroll
  for (int f = 0; f < 8; ++f) {
    const int rb = bm + wm * 128 + f * 16 + ks * 4;
#pragma unroll
    for (int j = 0; j < 4; ++j) {
      const int col = bn + wn * 64 + j * 16 + fr;
#pragma unroll
      for (int r = 0; r < 4; ++r) {
        const int row = rb + r;
        float v = acc[f][j][r];
        if (MODE == 0) v += aux[col];
        else           v += aux[(size_t)row * N + col];
        stv(&C[(size_t)row * N + col], v);
      }
    }
  }
}

// ---------------- launch ----------------
extern "C" void kernel_launch(void* const* d_in, const int* in_sizes, int n_in,
                              void* d_out, int out_size, void* d_ws, size_t ws_size,
                              hipStream_t stream) {
  (void)in_sizes; (void)n_in; (void)out_size; (void)ws_size;
  const float* x    = (const float*)d_in[0];
  const int*   pos  = (const int*)d_in[1];
  const float* ln_w = (const float*)d_in[2];
  const float* Wq   = (const float*)d_in[3];
  const float* bq   = (const float*)d_in[4];
  const float* Wo   = (const float*)d_in[9];
  float* out = (float*)d_out;

  char* ws = (char*)d_ws;
  size_t off = 0;
  bf16* h    = (bf16*)(ws + off); off += (size_t)NTOK * HIDDEN * sizeof(bf16);
  bf16* q    = (bf16*)(ws + off); off += (size_t)NTOK * NQ * sizeof(bf16);
  bf16* Wqb  = (bf16*)(ws + off); off += (size_t)NQ * HIDDEN * sizeof(bf16);
  bf16* Wob  = (bf16*)(ws + off); off += (size_t)HIDDEN * NQ * sizeof(bf16);
  float2* tab = (float2*)(ws + off); off += (size_t)NTOK * NPAIR * sizeof(float2);

  const int n4 = NQ * HIDDEN / 4;
  cvt_f32_bf16<<<(n4 + 255) / 256, 256, 0, stream>>>(Wq, Wqb, n4);
  cvt_f32_bf16<<<(n4 + 255) / 256, 256, 0, stream>>>(Wo, Wob, n4);
  rmsnorm_k<<<NTOK, 256, 0, stream>>>(x, ln_w, h);
  rope_tab_k<<<(NTOK * NPAIR) / 256, 256, 0, stream>>>(pos, tab);

  const int nblk = (NTOK / BMT) * (NQ / BNT);   // 32 * 14 = 448 (%8 == 0)
  gemm256<0, bf16><<<nblk, 512, 0, stream>>>(h, Wqb, bq, q, NTOK, NQ, HIDDEN);
  rope_apply_k<<<NTOK, 256, 0, stream>>>(q, tab);
  gemm256<1, float><<<nblk, 512, 0, stream>>>(q, Wob, x, out, NTOK, HIDDEN, NQ);
}